// Round 15
// baseline (584.664 us; speedup 1.0000x reference)
//
#include <hip/hip_runtime.h>

// Problem constants: B=32, L=2, F=65536, D=768
#define BB 32
#define LL 2
#define FF 65536
#define DD 768
#define F4 (FF / 4)        // 16384 groups of 4 f
#define LD (LL * DD)       // 1536
#define LD2 (LD / 2)       // 768 float2
#define D2 (DD / 2)        // 384 float2 per weight row
#define BL (BB * LD)       // 49152 outputs

#define FT_FLOAT4S ((size_t)F4 * BB)            // 524288 float4 = 8.39 MB
#define FT_BYTES   (FT_FLOAT4S * sizeof(float4))
#define CHUNK_BYTES ((size_t)BL * sizeof(float))  // 196608 B
#define TMP_BYTES  ((size_t)8 * BL * sizeof(float))
#define NFMAX 512
#define RND 16             // groups per LDS round

#define FMA2(A, W, S)                                                          \
    do {                                                                       \
        (A).x = fmaf((W).x, (S), (A).x);                                       \
        (A).y = fmaf((W).y, (S), (A).y);                                       \
    } while (0)

// FMA batch: 8 consecutive b from buffer P into acc[O..O+7]
#define FBATCH(P, O)                                                           \
    do {                                                                       \
        _Pragma("unroll")                                                      \
        for (int i = 0; i < 8; ++i) {                                          \
            float4 fv = (P)[i];                                                \
            FMA2(acc[(O) + i], wa0, fv.x);                                     \
            FMA2(acc[(O) + i], wa1, fv.y);                                     \
            FMA2(acc[(O) + i], wa2, fv.z);                                     \
            FMA2(acc[(O) + i], wa3, fv.w);                                     \
        }                                                                      \
    } while (0)

// Stage 0: transpose f (B x F) -> fT[g][b] as float4.
__global__ __launch_bounds__(256) void cc_transpose(
    const float4* __restrict__ f4, float4* __restrict__ fT4)
{
    size_t t = (size_t)blockIdx.x * 256 + threadIdx.x;   // 0 .. F4*32-1
    if (t >= FT_FLOAT4S) return;
    int b = (int)(t / F4);
    int g = (int)(t - (size_t)b * F4);
    fT4[(size_t)g * BB + b] = f4[t];
}

// Stage 1: partial GEMM over an F-chunk. float2 d-tile (128 d / wave).
// Decoupled memory queues:
//  - f: staged per 16-group round global->VGPR (issued at round start, OLDEST
//    in the vmcnt FIFO) -> ds_write -> inner loop reads via ds_read (lgkmcnt,
//    never gated by in-flight weight loads).
//  - weight: depth-2 prefetch (wa/wb/wc) on vmcnt; first use trails issue by
//    2 groups (~1024 cy) >= HBM latency, so weight waits are already retired.
// Single-wave block: no barriers, no vmcnt(0) drains.
// amdgpu_waves_per_eu(2,2): pin regalloc to the 256-VGPR budget. R6/R8/R13/R14
// all died to the allocator choosing higher occupancy and spilling acc.
// grid = (12, NF); block = 64.  ct: l = ct/6, dt = ct%6.
// partials[c][b][l*768 + dt*128 + lane*2]
__global__ __launch_bounds__(64)
__attribute__((amdgpu_waves_per_eu(2, 2)))
void cc_stage1(
    const float4* __restrict__ fT4,     // [F4][32] float4
    const float* __restrict__ weight,   // L x F x D
    float* __restrict__ partials,       // NF x B x LD
    int chunk4)
{
    __shared__ float4 lbuf[2][RND * BB];   // 2 x 8 KB

    const int lane = threadIdx.x;
    const int ct   = blockIdx.x;        // 0..11
    const int c    = blockIdx.y;        // chunk
    const int l    = ct / 6;
    const int dt   = ct - l * 6;

    const float2* __restrict__ w2p =
        (const float2*)weight + (size_t)l * FF * D2 + (size_t)dt * 64 + lane;

    int g0 = c * chunk4;
    int g1 = g0 + chunk4;
    if (g1 > F4) g1 = F4;

    float2 acc[BB];
#pragma unroll
    for (int b = 0; b < BB; ++b) acc[b] = make_float2(0.f, 0.f);

    float4 sF[8];

    // ---- prologue: stage round 0 into lbuf[0] ----
    {
        int cnt = g1 - g0; if (cnt > RND) cnt = RND;
        const int ne = cnt * BB;
#pragma unroll
        for (int i = 0; i < 8; ++i) {
            int idx = i * 64 + lane;
            if (idx < ne) sF[i] = fT4[(size_t)g0 * BB + idx];
        }
#pragma unroll
        for (int i = 0; i < 8; ++i) {
            int idx = i * 64 + lane;
            if (idx < ne) lbuf[0][idx] = sF[i];
        }
    }

    // depth-2 weight pipeline: wa = w(g0), wb = w(g0+1)
    int gb = (g0 + 1 < g1) ? (g0 + 1) : g0;
    float2 wa0 = w2p[((size_t)g0 * 4 + 0) * D2];
    float2 wa1 = w2p[((size_t)g0 * 4 + 1) * D2];
    float2 wa2 = w2p[((size_t)g0 * 4 + 2) * D2];
    float2 wa3 = w2p[((size_t)g0 * 4 + 3) * D2];
    float2 wb0 = w2p[((size_t)gb * 4 + 0) * D2];
    float2 wb1 = w2p[((size_t)gb * 4 + 1) * D2];
    float2 wb2 = w2p[((size_t)gb * 4 + 2) * D2];
    float2 wb3 = w2p[((size_t)gb * 4 + 3) * D2];

    float4 pA[8], pB[8];
    {
        const float4* fr = &lbuf[0][0];
#pragma unroll
        for (int i = 0; i < 8; ++i) pA[i] = fr[i];   // group g0, b0..7
    }

    int cur = 0;
    for (int gs = g0; gs < g1; gs += RND) {
        int gcnt = g1 - gs; if (gcnt > RND) gcnt = RND;
        int ns   = gs + gcnt;
        int ncnt = g1 - ns; if (ncnt > RND) ncnt = RND;

        // issue next round's f staging loads FIRST (oldest in vmcnt FIFO)
        if (ncnt > 0) {
            const int ne = ncnt * BB;
#pragma unroll
            for (int i = 0; i < 8; ++i) {
                int idx = i * 64 + lane;
                if (idx < ne) sF[i] = fT4[(size_t)ns * BB + idx];
            }
        }

        for (int gi = 0; gi < gcnt; ++gi) {
            const int g = gs + gi;
            int gnn = g + 2; if (gnn >= g1) gnn = g1 - 1;
            // weight for g+2 (vmcnt; 2-group cover >= HBM latency)
            float2 wc0 = w2p[((size_t)gnn * 4 + 0) * D2];
            float2 wc1 = w2p[((size_t)gnn * 4 + 1) * D2];
            float2 wc2 = w2p[((size_t)gnn * 4 + 2) * D2];
            float2 wc3 = w2p[((size_t)gnn * 4 + 3) * D2];

            const float4* fr = &lbuf[cur][gi * BB];

            // ping-pong f batches via LDS (lgkmcnt queue)
#pragma unroll
            for (int i = 0; i < 8; ++i) pB[i] = fr[8 + i];
            FBATCH(pA, 0);
#pragma unroll
            for (int i = 0; i < 8; ++i) pA[i] = fr[16 + i];
            FBATCH(pB, 8);
#pragma unroll
            for (int i = 0; i < 8; ++i) pB[i] = fr[24 + i];
            FBATCH(pA, 16);
            if (gi + 1 < gcnt) {
                const float4* frn = &lbuf[cur][(gi + 1) * BB];
#pragma unroll
                for (int i = 0; i < 8; ++i) pA[i] = frn[i];
            }
            FBATCH(pB, 24);

            // rotate weight pipeline
            wa0 = wb0; wa1 = wb1; wa2 = wb2; wa3 = wb3;
            wb0 = wc0; wb1 = wc1; wb2 = wc2; wb3 = wc3;
        }

        // round end: write staged f to the other buffer, load first batch
        if (ncnt > 0) {
            const int nxt = cur ^ 1;
            const int ne  = ncnt * BB;
#pragma unroll
            for (int i = 0; i < 8; ++i) {
                int idx = i * 64 + lane;
                if (idx < ne) lbuf[nxt][idx] = sF[i];
            }
            cur = nxt;
            const float4* fr = &lbuf[cur][0];
#pragma unroll
            for (int i = 0; i < 8; ++i) pA[i] = fr[i];
        }
    }

    float2* __restrict__ out2 =
        (float2*)partials + (size_t)c * BB * LD2 + (size_t)(l * 384 + dt * 64 + lane);
#pragma unroll
    for (int b = 0; b < BB; ++b)
        out2[(size_t)b * LD2] = acc[b];
}

// Stage 2a: 8-way tree partial reduce. grid (192, 8).
__global__ __launch_bounds__(256) void cc_stage2a(
    const float* __restrict__ partials,
    float* __restrict__ tmp,
    int nf, int cs)
{
    int o = blockIdx.x * 256 + threadIdx.x;   // 0 .. BL-1
    if (o >= BL) return;
    int j  = blockIdx.y;                      // 0..7
    int c0 = j * cs;
    int c1 = c0 + cs;
    if (c1 > nf) c1 = nf;
    float s = 0.f;
    const float* __restrict__ p = partials + (size_t)c0 * BL + o;
#pragma unroll 16
    for (int c = c0; c < c1; ++c, p += BL)
        s += *p;
    tmp[(size_t)j * BL + o] = s;
}

// Stage 2b: out[o] = bias[ld] + sum_j tmp[j][o]
__global__ __launch_bounds__(256) void cc_stage2b(
    const float* __restrict__ tmp,
    const float* __restrict__ bias,
    float* __restrict__ out)
{
    int o = blockIdx.x * 256 + threadIdx.x;
    if (o >= BL) return;
    int b  = o / LD;
    int ld = o - b * LD;
    float s = bias[ld];
#pragma unroll
    for (int j = 0; j < 8; ++j)
        s += tmp[(size_t)j * BL + o];
    out[o] = s;
}

// Correctness-only fallback if workspace is too small.
__global__ __launch_bounds__(256) void cc_direct(
    const float* __restrict__ f,
    const float* __restrict__ weight,
    const float* __restrict__ bias,
    float* __restrict__ out)
{
    int o = blockIdx.x * 256 + threadIdx.x;
    if (o >= BL) return;
    int b  = o / LD;
    int ld = o - b * LD;
    int l  = ld / DD;
    int d  = ld - l * DD;
    float s = bias[ld];
    const float* wp = weight + (size_t)l * FF * DD + d;
    const float* fp = f + (size_t)b * FF;
    for (int fi = 0; fi < FF; ++fi)
        s = fmaf(fp[fi], wp[(size_t)fi * DD], s);
    out[o] = s;
}

extern "C" void kernel_launch(void* const* d_in, const int* in_sizes, int n_in,
                              void* d_out, int out_size, void* d_ws, size_t ws_size,
                              hipStream_t stream)
{
    const float* f      = (const float*)d_in[0];   // 32 x 65536
    const float* weight = (const float*)d_in[1];   // 2 x 65536 x 768
    const float* bias   = (const float*)d_in[2];   // 2 x 768
    float* out          = (float*)d_out;           // 32 x 2 x 768

    if (ws_size < FT_BYTES + TMP_BYTES + CHUNK_BYTES) {
        cc_direct<<<(BL + 255) / 256, 256, 0, stream>>>(f, weight, bias, out);
        return;
    }

    int nf = (int)((ws_size - FT_BYTES - TMP_BYTES) / CHUNK_BYTES);
    if (nf > NFMAX) nf = NFMAX;
    int chunk4 = (F4 + nf - 1) / nf;        // 32 when nf=512
    nf = (F4 + chunk4 - 1) / chunk4;

    float4* fT4      = (float4*)d_ws;
    float*  partials = (float*)((char*)d_ws + FT_BYTES);
    float*  tmp      = (float*)((char*)d_ws + FT_BYTES + (size_t)nf * CHUNK_BYTES);

    cc_transpose<<<(int)((FT_FLOAT4S + 255) / 256), 256, 0, stream>>>(
        (const float4*)f, fT4);

    dim3 grid1(12, nf);
    cc_stage1<<<grid1, 64, 0, stream>>>(fT4, weight, partials, chunk4);

    int cs = (nf + 7) / 8;
    dim3 grid2a((BL + 255) / 256, 8);
    cc_stage2a<<<grid2a, 256, 0, stream>>>(partials, tmp, nf, cs);
    cc_stage2b<<<(BL + 255) / 256, 256, 0, stream>>>(tmp, bias, out);
}

// Round 16
// 169.553 us; speedup vs baseline: 3.4483x; 3.4483x over previous
//
#include <hip/hip_runtime.h>

// Problem constants: B=32, L=2, F=65536, D=768
#define BB 32
#define LL 2
#define FF 65536
#define DD 768
#define F4 (FF / 4)        // 16384 groups of 4 f
#define LD (LL * DD)       // 1536
#define LD2 (LD / 2)       // 768 float2
#define D2 (DD / 2)        // 384 float2 per weight row
#define BL (BB * LD)       // 49152 outputs

#define FT_FLOAT4S ((size_t)F4 * BB)            // 524288 float4 = 8.39 MB
#define FT_BYTES   (FT_FLOAT4S * sizeof(float4))
#define CHUNK_BYTES ((size_t)BL * sizeof(float))  // 196608 B
#define TMP_BYTES  ((size_t)8 * BL * sizeof(float))
#define NFMAX 512
#define RND 16             // groups per LDS round (chunk4 forced % 16 == 0)

#define FMA2(A, W, S)                                                          \
    do {                                                                       \
        (A).x = fmaf((W).x, (S), (A).x);                                       \
        (A).y = fmaf((W).y, (S), (A).y);                                       \
    } while (0)

// FMA batch: 8 consecutive b from buffer P into acc[O..O+7]
#define FBATCH(P, O)                                                           \
    do {                                                                       \
        _Pragma("unroll")                                                      \
        for (int i = 0; i < 8; ++i) {                                          \
            float4 fv = (P)[i];                                                \
            FMA2(acc[(O) + i], wa0, fv.x);                                     \
            FMA2(acc[(O) + i], wa1, fv.y);                                     \
            FMA2(acc[(O) + i], wa2, fv.z);                                     \
            FMA2(acc[(O) + i], wa3, fv.w);                                     \
        }                                                                      \
    } while (0)

// Stage 0: transpose f (B x F) -> fT[g][b] as float4.
__global__ __launch_bounds__(256) void cc_transpose(
    const float4* __restrict__ f4, float4* __restrict__ fT4)
{
    size_t t = (size_t)blockIdx.x * 256 + threadIdx.x;   // 0 .. F4*32-1
    if (t >= FT_FLOAT4S) return;
    int b = (int)(t / F4);
    int g = (int)(t - (size_t)b * F4);
    fT4[(size_t)g * BB + b] = f4[t];
}

// Stage 1: partial GEMM over an F-chunk. float2 d-tile (128 d / wave).
// Decoupled memory queues:
//  - f: per 16-group round, global->VGPR sF (8x dwordx4/lane, issued at round
//    start = oldest in vmcnt FIFO, retired long before any wait) -> ds_write
//    -> inner loop refills pA/pB via ds_read (lgkmcnt — never gated by the
//    in-flight weight stream).
//  - weight: depth-2 prefetch (wa/wb/wc) on vmcnt; first use trails issue by
//    ~2 groups (~1000 cy) >= HBM latency.
// Single-wave block: no barriers, no vmcnt(0) drains.
// __launch_bounds__(64, 2): the ONLY attribute measured to allocate ~240 VGPR
// without spilling (R12). waves_per_eu(2,2) and (64,1)/(256,4)/(64,3) all
// produced caps of 64-144 and catastrophic scratch spill (R6/R8/R13/R14/R15).
// grid = (12, NF); block = 64.  ct: l = ct/6, dt = ct%6.
// partials[c][b][l*768 + dt*128 + lane*2]
__global__ __launch_bounds__(64, 2) void cc_stage1(
    const float4* __restrict__ fT4,     // [F4][32] float4
    const float* __restrict__ weight,   // L x F x D
    float* __restrict__ partials,       // NF x B x LD
    int chunk4)                          // multiple of RND
{
    __shared__ float4 lbuf[2][RND * BB];   // 2 x 8 KB

    const int lane = threadIdx.x;
    const int ct   = blockIdx.x;        // 0..11
    const int c    = blockIdx.y;        // chunk
    const int l    = ct / 6;
    const int dt   = ct - l * 6;

    const float2* __restrict__ w2p =
        (const float2*)weight + (size_t)l * FF * D2 + (size_t)dt * 64 + lane;

    int g0 = c * chunk4;
    int g1 = g0 + chunk4;
    if (g1 > F4) g1 = F4;              // g1-g0 stays a multiple of RND

    float2 acc[BB];
#pragma unroll
    for (int b = 0; b < BB; ++b) acc[b] = make_float2(0.f, 0.f);

    float4 sF[8];

    // ---- prologue: stage round 0 (exactly RND*32 = 512 float4, 8/lane) ----
#pragma unroll
    for (int i = 0; i < 8; ++i)
        sF[i] = fT4[(size_t)g0 * BB + i * 64 + lane];
#pragma unroll
    for (int i = 0; i < 8; ++i)
        lbuf[0][i * 64 + lane] = sF[i];

    // depth-2 weight pipeline: wa = w(g0), wb = w(g0+1)
    int gb = (g0 + 1 < g1) ? (g0 + 1) : g0;
    float2 wa0 = w2p[((size_t)g0 * 4 + 0) * D2];
    float2 wa1 = w2p[((size_t)g0 * 4 + 1) * D2];
    float2 wa2 = w2p[((size_t)g0 * 4 + 2) * D2];
    float2 wa3 = w2p[((size_t)g0 * 4 + 3) * D2];
    float2 wb0 = w2p[((size_t)gb * 4 + 0) * D2];
    float2 wb1 = w2p[((size_t)gb * 4 + 1) * D2];
    float2 wb2 = w2p[((size_t)gb * 4 + 2) * D2];
    float2 wb3 = w2p[((size_t)gb * 4 + 3) * D2];

    float4 pA[8], pB[8];
    {
        const float4* fr = &lbuf[0][0];
#pragma unroll
        for (int i = 0; i < 8; ++i) pA[i] = fr[i];   // group g0, b0..7
    }

    int cur = 0;
    for (int gs = g0; gs < g1; gs += RND) {
        const int ns   = gs + RND;
        const bool more = ns < g1;

        // issue next round's f staging loads FIRST (oldest in vmcnt FIFO)
        if (more) {
#pragma unroll
            for (int i = 0; i < 8; ++i)
                sF[i] = fT4[(size_t)ns * BB + i * 64 + lane];
        }

        for (int gi = 0; gi < RND; ++gi) {
            const int g = gs + gi;
            int gnn = g + 2; if (gnn >= g1) gnn = g1 - 1;
            // weight for g+2 (vmcnt; 2-group cover >= HBM latency)
            float2 wc0 = w2p[((size_t)gnn * 4 + 0) * D2];
            float2 wc1 = w2p[((size_t)gnn * 4 + 1) * D2];
            float2 wc2 = w2p[((size_t)gnn * 4 + 2) * D2];
            float2 wc3 = w2p[((size_t)gnn * 4 + 3) * D2];

            const float4* fr = &lbuf[cur][gi * BB];

            // ping-pong f batches via LDS (lgkmcnt queue)
#pragma unroll
            for (int i = 0; i < 8; ++i) pB[i] = fr[8 + i];
            FBATCH(pA, 0);
#pragma unroll
            for (int i = 0; i < 8; ++i) pA[i] = fr[16 + i];
            FBATCH(pB, 8);
#pragma unroll
            for (int i = 0; i < 8; ++i) pB[i] = fr[24 + i];
            FBATCH(pA, 16);
            if (gi + 1 < RND) {
                const float4* frn = &lbuf[cur][(gi + 1) * BB];
#pragma unroll
                for (int i = 0; i < 8; ++i) pA[i] = frn[i];
            }
            FBATCH(pB, 24);

            // rotate weight pipeline
            wa0 = wb0; wa1 = wb1; wa2 = wb2; wa3 = wb3;
            wb0 = wc0; wb1 = wc1; wb2 = wc2; wb3 = wc3;
        }

        // round end: write staged f to the other buffer, refill pA
        if (more) {
            const int nxt = cur ^ 1;
#pragma unroll
            for (int i = 0; i < 8; ++i)
                lbuf[nxt][i * 64 + lane] = sF[i];
            cur = nxt;
            const float4* fr = &lbuf[cur][0];
#pragma unroll
            for (int i = 0; i < 8; ++i) pA[i] = fr[i];
        }
    }

    float2* __restrict__ out2 =
        (float2*)partials + (size_t)c * BB * LD2 + (size_t)(l * 384 + dt * 64 + lane);
#pragma unroll
    for (int b = 0; b < BB; ++b)
        out2[(size_t)b * LD2] = acc[b];
}

// Stage 2a: 8-way tree partial reduce. grid (192, 8).
__global__ __launch_bounds__(256) void cc_stage2a(
    const float* __restrict__ partials,
    float* __restrict__ tmp,
    int nf, int cs)
{
    int o = blockIdx.x * 256 + threadIdx.x;   // 0 .. BL-1
    if (o >= BL) return;
    int j  = blockIdx.y;                      // 0..7
    int c0 = j * cs;
    int c1 = c0 + cs;
    if (c1 > nf) c1 = nf;
    float s = 0.f;
    const float* __restrict__ p = partials + (size_t)c0 * BL + o;
#pragma unroll 16
    for (int c = c0; c < c1; ++c, p += BL)
        s += *p;
    tmp[(size_t)j * BL + o] = s;
}

// Stage 2b: out[o] = bias[ld] + sum_j tmp[j][o]
__global__ __launch_bounds__(256) void cc_stage2b(
    const float* __restrict__ tmp,
    const float* __restrict__ bias,
    float* __restrict__ out)
{
    int o = blockIdx.x * 256 + threadIdx.x;
    if (o >= BL) return;
    int b  = o / LD;
    int ld = o - b * LD;
    float s = bias[ld];
#pragma unroll
    for (int j = 0; j < 8; ++j)
        s += tmp[(size_t)j * BL + o];
    out[o] = s;
}

// Correctness-only fallback if workspace is too small.
__global__ __launch_bounds__(256) void cc_direct(
    const float* __restrict__ f,
    const float* __restrict__ weight,
    const float* __restrict__ bias,
    float* __restrict__ out)
{
    int o = blockIdx.x * 256 + threadIdx.x;
    if (o >= BL) return;
    int b  = o / LD;
    int ld = o - b * LD;
    int l  = ld / DD;
    int d  = ld - l * DD;
    float s = bias[ld];
    const float* wp = weight + (size_t)l * FF * DD + d;
    const float* fp = f + (size_t)b * FF;
    for (int fi = 0; fi < FF; ++fi)
        s = fmaf(fp[fi], wp[(size_t)fi * DD], s);
    out[o] = s;
}

extern "C" void kernel_launch(void* const* d_in, const int* in_sizes, int n_in,
                              void* d_out, int out_size, void* d_ws, size_t ws_size,
                              hipStream_t stream)
{
    const float* f      = (const float*)d_in[0];   // 32 x 65536
    const float* weight = (const float*)d_in[1];   // 2 x 65536 x 768
    const float* bias   = (const float*)d_in[2];   // 2 x 768
    float* out          = (float*)d_out;           // 32 x 2 x 768

    if (ws_size < FT_BYTES + TMP_BYTES + CHUNK_BYTES) {
        cc_direct<<<(BL + 255) / 256, 256, 0, stream>>>(f, weight, bias, out);
        return;
    }

    int nf = (int)((ws_size - FT_BYTES - TMP_BYTES) / CHUNK_BYTES);
    if (nf > NFMAX) nf = NFMAX;
    // chunk4 multiple of RND so every LDS round is a full, branch-free 16
    int chunk4 = (F4 + nf - 1) / nf;
    chunk4 = (chunk4 + RND - 1) & ~(RND - 1);
    nf = (F4 + chunk4 - 1) / chunk4;

    float4* fT4      = (float4*)d_ws;
    float*  partials = (float*)((char*)d_ws + FT_BYTES);
    float*  tmp      = (float*)((char*)d_ws + FT_BYTES + (size_t)nf * CHUNK_BYTES);

    cc_transpose<<<(int)((FT_FLOAT4S + 255) / 256), 256, 0, stream>>>(
        (const float4*)f, fT4);

    dim3 grid1(12, nf);
    cc_stage1<<<grid1, 64, 0, stream>>>(fT4, weight, partials, chunk4);

    int cs = (nf + 7) / 8;
    dim3 grid2a((BL + 255) / 256, 8);
    cc_stage2a<<<grid2a, 256, 0, stream>>>(partials, tmp, nf, cs);
    cc_stage2b<<<(BL + 255) / 256, 256, 0, stream>>>(tmp, bias, out);
}

// Round 17
// 100.839 us; speedup vs baseline: 5.7980x; 1.6814x over previous
//
#include <hip/hip_runtime.h>

// Problem constants: B=32, L=2, F=65536, D=768
#define BB 32
#define LL 2
#define FF 65536
#define DD 768
#define F4 (FF / 4)        // 16384 float4 per f row
#define LD (LL * DD)       // 1536
#define BL (BB * LD)       // 49152 outputs

#define NSTEPS (FF / 16)   // 4096 K16-steps
#define APREP_BYTES ((size_t)NSTEPS * 64 * 16)      // 4 MB
#define CHUNK_BYTES ((size_t)BL * sizeof(float))    // 196608 B
#define TMP_BYTES  ((size_t)8 * BL * sizeof(float))
#define NF 128             // F-chunks
#define KS (NSTEPS / NF)   // 32 K16-steps per chunk

typedef __attribute__((ext_vector_type(8)))  short short8;   // 8 bf16 (4 VGPR)
typedef __attribute__((ext_vector_type(16))) float float16;  // 16 fp32 acc

// fp32 -> bf16 round-to-nearest-even (finite inputs)
static __device__ __forceinline__ unsigned bf16rne(float x)
{
    unsigned u = __float_as_uint(x);
    return (u + 0x7fffu + ((u >> 16) & 1u)) >> 16;
}
static __device__ __forceinline__ unsigned packbf(float a, float b)
{
    return bf16rne(a) | (bf16rne(b) << 16);
}

// Prep: build A-fragments. aprep[s][lane] (uint4, 16B) holds, packed as
// 4 VGPRs x 2 bf16, A[row = lane&31][k = s*16 + (lane>>5)*8 + j], j=0..7,
// with A[b][k] = f[b][k]. One dwordx4 per lane per K-step in the GEMM.
__global__ __launch_bounds__(256) void cc_prep_a(
    const float4* __restrict__ f4,     // [32][16384]
    uint4* __restrict__ aprep)         // [4096][64]
{
    int t = blockIdx.x * 256 + threadIdx.x;      // 0 .. 4096*64-1
    if (t >= NSTEPS * 64) return;
    int s = t >> 6;
    int l = t & 63;
    int b = l & 31;
    int k0 = s * 16 + ((l >> 5) << 3);           // multiple of 8
    float4 fa = f4[(size_t)b * F4 + (k0 >> 2)];
    float4 fb = f4[(size_t)b * F4 + (k0 >> 2) + 1];
    uint4 u;
    u.x = packbf(fa.x, fa.y);
    u.y = packbf(fa.z, fa.w);
    u.z = packbf(fb.x, fb.y);
    u.w = packbf(fb.z, fb.w);
    aprep[t] = u;
}

// Stage 1: MFMA partial GEMM. grid = (24, NF); block = 64 (one wave).
// Wave tile: M=32 (all batches) x N=64 (two 32x32 n-tiles), K-chunk = KS*16.
// Per K16-step: 1 dwordx4 A-frag load + 16 dword weight loads (each = two
// aligned 128B cachelines) + 16 bf16 cvt-packs + 2 mfma_32x32x16_bf16.
// acc 32 VGPR -> ~100 total; (64,4) caps at 128, 4 waves/SIMD for TLP.
// C/D layout: col = lane&31, row = (r&3) + 8*(r>>2) + 4*(lane>>5).
__global__ __launch_bounds__(64, 4) void cc_mfma(
    const uint4* __restrict__ aprep,   // [4096][64]
    const float* __restrict__ weight,  // [2][65536][768]
    float* __restrict__ partials)      // [NF][32][1536]
{
    const int lane = threadIdx.x;
    const int ct   = blockIdx.x;       // 0..23 -> 64-wide d-tile
    const int c    = blockIdx.y;       // 0..NF-1
    const int nd0  = ct * 64;
    const int l    = nd0 / DD;
    const int d0   = nd0 - l * DD;

    const int col  = lane & 31;
    const int krow = (lane >> 5) << 3; // 0 or 8

    const float* __restrict__ wbase =
        weight + (size_t)l * FF * DD + d0 + col;

    float16 acc0, acc1;
#pragma unroll
    for (int i = 0; i < 16; ++i) { acc0[i] = 0.f; acc1[i] = 0.f; }

    const int s0 = c * KS;
    for (int s = s0; s < s0 + KS; ++s) {
        uint4 av = aprep[(size_t)s * 64 + lane];
        short8 a8 = __builtin_bit_cast(short8, av);

        const float* __restrict__ wr = wbase + (size_t)(s * 16 + krow) * DD;
        float wv0[8], wv1[8];
#pragma unroll
        for (int j = 0; j < 8; ++j) {
            wv0[j] = wr[j * DD];        // n-tile 0: d = d0 + col
            wv1[j] = wr[j * DD + 32];   // n-tile 1: d = d0 + 32 + col
        }
        short8 b0, b1;
#pragma unroll
        for (int jj = 0; jj < 4; ++jj) {
            b0[2 * jj]     = (short)bf16rne(wv0[2 * jj]);
            b0[2 * jj + 1] = (short)bf16rne(wv0[2 * jj + 1]);
            b1[2 * jj]     = (short)bf16rne(wv1[2 * jj]);
            b1[2 * jj + 1] = (short)bf16rne(wv1[2 * jj + 1]);
        }
        acc0 = __builtin_amdgcn_mfma_f32_32x32x16_bf16(a8, b0, acc0, 0, 0, 0);
        acc1 = __builtin_amdgcn_mfma_f32_32x32x16_bf16(a8, b1, acc1, 0, 0, 0);
    }

    float* __restrict__ pp =
        partials + (size_t)c * BL + (size_t)(l * DD + d0 + col);
#pragma unroll
    for (int r = 0; r < 16; ++r) {
        int b = (r & 3) + 8 * (r >> 2) + 4 * (lane >> 5);
        pp[(size_t)b * LD]      = acc0[r];
        pp[(size_t)b * LD + 32] = acc1[r];
    }
}

// Stage 2a: 8-way tree partial reduce. grid (192, 8).
__global__ __launch_bounds__(256) void cc_stage2a(
    const float* __restrict__ partials,
    float* __restrict__ tmp,
    int nf, int cs)
{
    int o = blockIdx.x * 256 + threadIdx.x;   // 0 .. BL-1
    if (o >= BL) return;
    int j  = blockIdx.y;                      // 0..7
    int c0 = j * cs;
    int c1 = c0 + cs;
    if (c1 > nf) c1 = nf;
    float s = 0.f;
    const float* __restrict__ p = partials + (size_t)c0 * BL + o;
#pragma unroll 16
    for (int c = c0; c < c1; ++c, p += BL)
        s += *p;
    tmp[(size_t)j * BL + o] = s;
}

// Stage 2b: out[o] = bias[ld] + sum_j tmp[j][o]
__global__ __launch_bounds__(256) void cc_stage2b(
    const float* __restrict__ tmp,
    const float* __restrict__ bias,
    float* __restrict__ out)
{
    int o = blockIdx.x * 256 + threadIdx.x;
    if (o >= BL) return;
    int b  = o / LD;
    int ld = o - b * LD;
    float s = bias[ld];
#pragma unroll
    for (int j = 0; j < 8; ++j)
        s += tmp[(size_t)j * BL + o];
    out[o] = s;
}

// Correctness-only fallback if workspace is too small (fp32 path).
__global__ __launch_bounds__(256) void cc_direct(
    const float* __restrict__ f,
    const float* __restrict__ weight,
    const float* __restrict__ bias,
    float* __restrict__ out)
{
    int o = blockIdx.x * 256 + threadIdx.x;
    if (o >= BL) return;
    int b  = o / LD;
    int ld = o - b * LD;
    int l  = ld / DD;
    int d  = ld - l * DD;
    float s = bias[ld];
    const float* wp = weight + (size_t)l * FF * DD + d;
    const float* fp = f + (size_t)b * FF;
    for (int fi = 0; fi < FF; ++fi)
        s = fmaf(fp[fi], wp[(size_t)fi * DD], s);
    out[o] = s;
}

extern "C" void kernel_launch(void* const* d_in, const int* in_sizes, int n_in,
                              void* d_out, int out_size, void* d_ws, size_t ws_size,
                              hipStream_t stream)
{
    const float* f      = (const float*)d_in[0];   // 32 x 65536
    const float* weight = (const float*)d_in[1];   // 2 x 65536 x 768
    const float* bias   = (const float*)d_in[2];   // 2 x 768
    float* out          = (float*)d_out;           // 32 x 2 x 768

    const size_t need = APREP_BYTES + (size_t)NF * CHUNK_BYTES + TMP_BYTES;
    if (ws_size < need) {
        cc_direct<<<(BL + 255) / 256, 256, 0, stream>>>(f, weight, bias, out);
        return;
    }

    uint4* aprep     = (uint4*)d_ws;
    float* partials  = (float*)((char*)d_ws + APREP_BYTES);
    float* tmp       = (float*)((char*)d_ws + APREP_BYTES + (size_t)NF * CHUNK_BYTES);

    cc_prep_a<<<(NSTEPS * 64 + 255) / 256, 256, 0, stream>>>(
        (const float4*)f, aprep);

    dim3 grid1(24, NF);
    cc_mfma<<<grid1, 64, 0, stream>>>(aprep, weight, partials);

    dim3 grid2a((BL + 255) / 256, 8);
    cc_stage2a<<<grid2a, 256, 0, stream>>>(partials, tmp, NF, NF / 8);
    cc_stage2b<<<(BL + 255) / 256, 256, 0, stream>>>(tmp, bias, out);
}